// Round 4
// baseline (110291.016 us; speedup 1.0000x reference)
//
#include <hip/hip_runtime.h>
#include <math.h>

// ---------------- problem constants ----------------
#define TSTEPS 400

// GEMV1: K1=1792 (x 0..255 bf16 | ctx 256..767 | h1 768..1791), W split at 768
//   224 blocks = 32 colgrp(128 cols) x 7 ksp(256 k = 2 ksub x 128)
// GEMV2: K2=2560 (h1 0..1023 | ctx 1024..1535 | h2 1536..2559), W split at 1536
//   256 blocks = 32 colgrp(128 cols) x 8 ksp(320 k = 2 ksub x 160)
#define KSP1 7
#define KSP2 8

// ---------------- workspace layout (float offsets) ----------------
#define OFF_XPRE  0u          // prenet out, BF16 [t][k][b]: 400*256*32 ushort = 1,638,400 float-slots
#define OFF_PM    1638400u    // tanh(memory@wm) fp32 [b][t][128]  (819,200)
#define OFF_IN1T  2457600u    // lstm1 input rows 256..1791, [(k-256)][b] (49,152)
#define OFF_IN2T  2506752u    // lstm2 input rows [k][b] (81,920)
#define OFF_ZP1   2588672u    // gemv1 partials [7][32][4096] (917,504)
#define OFF_ZP2   3506176u    // gemv2 partials [8][32][4096] (1,048,576)
#define OFF_CTXP  4554752u    // ctx 4-deep buffer [t&3][b][512] (65,536)
#define OFF_H2B   4620288u    // h2 2-deep buffer [parity][k][b] (65,536)
#define OFF_C1    4685824u    // c1 [b][1024] (32,768)
#define OFF_C2    4718592u    // c2 (32,768)
#define OFF_ATTW  4751360u    // att_w [b][200] (6,400)
#define OFF_CUM   4757760u    // att_w_cum (6,400)
#define WS_FLOATS 4764160u    // 19.06 MB (<= proven-available 24.9 MB)

// output layout (floats)
#define OUT_GATE  1024000   // 32*80*400
#define OUT_ALIGN 1036800   // + 32*400

__device__ __forceinline__ float sigf(float x)   { return 1.f / (1.f + __expf(-x)); }
__device__ __forceinline__ float tanhf_(float x) { return 1.f - 2.f / (__expf(2.f*x) + 1.f); }

// ---------------- P1: prenet for all 400 frames -> bf16 [t][k][b] ----------------
__global__ void __launch_bounds__(256) prenet_kernel(
    const float* __restrict__ dec, const float* __restrict__ w0, const float* __restrict__ b0,
    const float* __restrict__ w1, const float* __restrict__ b1, float* __restrict__ ws)
{
    __shared__ float s_in[80];
    __shared__ float s_h0[256];
    int t = blockIdx.x, b = blockIdx.y, tid = threadIdx.x;
    if (tid < 80) s_in[tid] = (t == 0) ? 0.f : dec[b*32000 + tid*400 + (t-1)];
    __syncthreads();
    float s = b0[tid];
    for (int m = 0; m < 80; ++m) s = fmaf(s_in[m], w0[m*256 + tid], s);
    s_h0[tid] = fmaxf(s, 0.f);
    __syncthreads();
    float s2 = b1[tid];
    for (int k = 0; k < 256; ++k) s2 = fmaf(s_h0[k], w1[k*256 + tid], s2);
    float v = fmaxf(s2, 0.f);
    unsigned u = __float_as_uint(v);
    u += 0x7fffu + ((u >> 16) & 1u);                     // RNE to bf16
    ((unsigned short*)(ws + OFF_XPRE))[(size_t)t*8192 + tid*32 + b] = (unsigned short)(u >> 16);
}

// ---------------- P2: processed_memory = tanh(memory @ wm), fp32 ----------------
__global__ void __launch_bounds__(128) pmem_kernel(
    const float* __restrict__ mp, const float* __restrict__ wm, float* __restrict__ ws)
{
    int t = blockIdx.x, b = blockIdx.y, a = threadIdx.x;
    const float* mrow = mp + (b*200 + t)*512;
    float s = 0.f;
    for (int d = 0; d < 512; ++d) s = fmaf(mrow[d], wm[d*128 + a], s);
    ws[OFF_PM + (b*200 + t)*128 + a] = tanhf_(s);
}

// ---------------- P3: zero recurrent state ----------------
__global__ void __launch_bounds__(256) zero_kernel(float* __restrict__ ws)
{
    int gid = blockIdx.x*256 + threadIdx.x, gsz = gridDim.x*256;
    for (int i = gid; i < 49152; i += gsz) ws[OFF_IN1T + i] = 0.f;
    for (int i = gid; i < 81920; i += gsz) ws[OFF_IN2T + i] = 0.f;
    for (int i = gid; i < 32768; i += gsz) { ws[OFF_C1 + i] = 0.f; ws[OFF_C2 + i] = 0.f; }
    for (int i = gid; i < 65536; i += gsz) { ws[OFF_CTXP + i] = 0.f; ws[OFF_H2B + i] = 0.f; }
    for (int i = gid; i < 6400;  i += gsz) { ws[OFF_ATTW + i] = 0.f; ws[OFF_CUM + i] = 0.f; }
}

// per-k FMA: 4 batches (x.xyzw) x 4 cols (w.xyzw) into a[0..3]
#define FMA4(X, W)                                                                                    \
    a[0].x = fmaf(X.x, W.x, a[0].x); a[0].y = fmaf(X.x, W.y, a[0].y); a[0].z = fmaf(X.x, W.z, a[0].z); a[0].w = fmaf(X.x, W.w, a[0].w); \
    a[1].x = fmaf(X.y, W.x, a[1].x); a[1].y = fmaf(X.y, W.y, a[1].y); a[1].z = fmaf(X.y, W.z, a[1].z); a[1].w = fmaf(X.y, W.w, a[1].w); \
    a[2].x = fmaf(X.z, W.x, a[2].x); a[2].y = fmaf(X.z, W.y, a[2].y); a[2].z = fmaf(X.z, W.z, a[2].z); a[2].w = fmaf(X.z, W.w, a[2].w); \
    a[3].x = fmaf(X.w, W.x, a[3].x); a[3].y = fmaf(X.w, W.y, a[3].y); a[3].z = fmaf(X.w, W.z, a[3].z); a[3].w = fmaf(X.w, W.w, a[3].w)

// ================================================================
// Phase kernel P1:
//   blocks 0..223   gemv1(t)
//   blocks 224..479 gemv2(t-1)
//   blocks 480..519 mel(t-2)      (off critical path, hides under gemv)
//   block  520      stop(t-2)
// gemv: 512 thr = 32 jq(4 cols) x 8 bgrp(4 batches) x 2 ksub.
// x slice staged in LDS; weights 8-deep register pipeline (8 loads in
// flight per wave while 128 FMAs cover).
// ================================================================
__global__ void __launch_bounds__(512, 4) kernel_P1(
    const float* __restrict__ l1k, const float* __restrict__ l1r,
    const float* __restrict__ l2k, const float* __restrict__ l2r,
    const float* __restrict__ fw, const float* __restrict__ fb,
    const float* __restrict__ sw, const float* __restrict__ sb,
    float* __restrict__ ws, float* __restrict__ out, int t)
{
    __shared__ float s_lds[10240];   // x-stage (<=10240) | combine 4096 (aliased after barrier)
    const int tid = threadIdx.x, bid = blockIdx.x;

    if (bid < 480) {
        const int jq = tid & 31, bgrp = (tid >> 5) & 7, ksub = tid >> 8;
        const int b0 = bgrp*4;
        float4 a[4];
#pragma unroll
        for (int i = 0; i < 4; ++i) a[i] = make_float4(0.f, 0.f, 0.f, 0.f);

        if (bid < 224) {
            if (t >= TSTEPS) return;
            // -------- gemv1(t): block = 128 cols x 256 k --------
            const int colgrp = bid & 31, ksp = bid >> 5;
            const int j = colgrp*128 + jq*4;

            // stage x slice (256 k x 32 b) into LDS
            if (ksp == 0) {
                const uint4* src = (const uint4*)((const unsigned short*)(ws + OFF_XPRE) + (size_t)t*8192);
                for (int i = tid; i < 1024; i += 512) {
                    uint4 p = src[i];
                    float* d = s_lds + i*8;
                    d[0] = __uint_as_float(p.x << 16); d[1] = __uint_as_float(p.x & 0xffff0000u);
                    d[2] = __uint_as_float(p.y << 16); d[3] = __uint_as_float(p.y & 0xffff0000u);
                    d[4] = __uint_as_float(p.z << 16); d[5] = __uint_as_float(p.z & 0xffff0000u);
                    d[6] = __uint_as_float(p.w << 16); d[7] = __uint_as_float(p.w & 0xffff0000u);
                }
            } else {
                const float4* src = (const float4*)(ws + OFF_IN1T - 8192 + (size_t)ksp*256*32);
                float4* dst = (float4*)s_lds;
                for (int i = tid; i < 2048; i += 512) dst[i] = src[i];
            }
            __syncthreads();

            // 128 k per ksub, 16 stages of 8, 8-deep prefetch
            // ksp k-range is entirely one side of the 768 split (256 | 768)
            const int kl0 = ksub*128;
            const int kg0 = ksp*256 + kl0;
            const float* wb = (ksp < 3) ? (l1k + (size_t)kg0*4096 + j)
                                        : (l1r + (size_t)(kg0 - 768)*4096 + j);
            const float* xb = s_lds + kl0*32 + b0;
            float4 wc[8], wn[8];
#pragma unroll
            for (int i = 0; i < 8; ++i) wc[i] = *(const float4*)(wb + (size_t)i*4096);
            for (int kk = 0; kk < 120; kk += 8) {
#pragma unroll
                for (int i = 0; i < 8; ++i) wn[i] = *(const float4*)(wb + (size_t)(kk + 8 + i)*4096);
#pragma unroll
                for (int i = 0; i < 8; ++i) {
                    float4 x = *(const float4*)(xb + (kk + i)*32);
                    FMA4(x, wc[i]);
                }
#pragma unroll
                for (int i = 0; i < 8; ++i) wc[i] = wn[i];
            }
#pragma unroll
            for (int i = 0; i < 8; ++i) {
                float4 x = *(const float4*)(xb + (120 + i)*32);
                FMA4(x, wc[i]);
            }

            // combine 2 ksubs via LDS (alias x region after barrier)
            __syncthreads();
            if (ksub) {
#pragma unroll
                for (int i = 0; i < 4; ++i)
                    *(float4*)(s_lds + (b0 + i)*128 + jq*4) = a[i];
            }
            __syncthreads();
            if (!ksub) {
                float* zp1 = ws + OFF_ZP1;
#pragma unroll
                for (int i = 0; i < 4; ++i) {
                    float4 r = *(const float4*)(s_lds + (b0 + i)*128 + jq*4);
                    a[i].x += r.x; a[i].y += r.y; a[i].z += r.z; a[i].w += r.w;
                    *(float4*)(zp1 + (size_t)(ksp*32 + b0 + i)*4096 + j) = a[i];
                }
            }
        } else {
            if (t < 1 || t > TSTEPS) return;
            // -------- gemv2(t-1): block = 128 cols x 320 k --------
            const int g = bid - 224;
            const int colgrp = g & 31, ksp = g >> 5;
            const int j = colgrp*128 + jq*4;

            {   // stage x slice (320 k x 32 b)
                const float4* src = (const float4*)(ws + OFF_IN2T + (size_t)ksp*320*32);
                float4* dst = (float4*)s_lds;
                for (int i = tid; i < 2560; i += 512) dst[i] = src[i];
            }
            __syncthreads();

            // 160 k per ksub, 20 stages of 8; 1536 split handled per-load
            const int kl0 = ksub*160;
            const int kg0 = ksp*320 + kl0;
            const float* xb = s_lds + kl0*32 + b0;
            float4 wc[8], wn[8];
#pragma unroll
            for (int i = 0; i < 8; ++i) {
                int kg = kg0 + i;
                const float* wr = (kg < 1536) ? (l2k + (size_t)kg*4096)
                                              : (l2r + (size_t)(kg - 1536)*4096);
                wc[i] = *(const float4*)(wr + j);
            }
            for (int kk = 0; kk < 152; kk += 8) {
#pragma unroll
                for (int i = 0; i < 8; ++i) {
                    int kg = kg0 + kk + 8 + i;
                    const float* wr = (kg < 1536) ? (l2k + (size_t)kg*4096)
                                                  : (l2r + (size_t)(kg - 1536)*4096);
                    wn[i] = *(const float4*)(wr + j);
                }
#pragma unroll
                for (int i = 0; i < 8; ++i) {
                    float4 x = *(const float4*)(xb + (kk + i)*32);
                    FMA4(x, wc[i]);
                }
#pragma unroll
                for (int i = 0; i < 8; ++i) wc[i] = wn[i];
            }
#pragma unroll
            for (int i = 0; i < 8; ++i) {
                float4 x = *(const float4*)(xb + (152 + i)*32);
                FMA4(x, wc[i]);
            }

            __syncthreads();
            if (ksub) {
#pragma unroll
                for (int i = 0; i < 4; ++i)
                    *(float4*)(s_lds + (b0 + i)*128 + jq*4) = a[i];
            }
            __syncthreads();
            if (!ksub) {
                float* zp2 = ws + OFF_ZP2;
#pragma unroll
                for (int i = 0; i < 4; ++i) {
                    float4 r = *(const float4*)(s_lds + (b0 + i)*128 + jq*4);
                    a[i].x += r.x; a[i].y += r.y; a[i].z += r.z; a[i].w += r.w;
                    *(float4*)(zp2 + (size_t)(ksp*32 + b0 + i)*4096 + j) = a[i];
                }
            }
        }
    } else if (bid < 520) {
        if (t < 2 || t > TSTEPS + 1) return;
        // -------- mel(t-2): 40 blocks x 2 mel-cols, 8 kh x 192 k --------
        const int t2 = t - 2;
        const int mc = bid - 480;
        const int m_l = tid & 1, b = (tid >> 1) & 31, kh = tid >> 6;  // kh 0..7
        const int m = mc*2 + m_l;
        const float* cp  = ws + OFF_CTXP + (size_t)((t2 & 3)*32 + b)*512;
        const float* h2b = ws + OFF_H2B + (size_t)(t2 & 1)*32768;
        float s = 0.f;
#pragma unroll 8
        for (int k = kh*192; k < kh*192 + 192; ++k) {
            float dv = (k < 1024) ? h2b[k*32 + b] : cp[k - 1024];
            s = fmaf(dv, fw[k*80 + m], s);
        }
        s_lds[tid] = s;   // tid = kh*64 + b*2 + m_l
        __syncthreads();
        if (tid < 64) {
            float v = 0.f;
#pragma unroll
            for (int kh2 = 0; kh2 < 8; ++kh2) v += s_lds[kh2*64 + tid];
            int b2 = tid >> 1, m2 = mc*2 + (tid & 1);
            out[(b2*80 + m2)*400 + t2] = v + fb[m2];
        }
    } else {
        if (t < 2 || t > TSTEPS + 1) return;
        // -------- stop(t-2): 32 b x 16 kh x 96 k --------
        const int t2 = t - 2;
        const int b = tid >> 4, kh = tid & 15;
        const float* cp  = ws + OFF_CTXP + (size_t)((t2 & 3)*32 + b)*512;
        const float* h2b = ws + OFF_H2B + (size_t)(t2 & 1)*32768;
        float s = 0.f;
#pragma unroll 8
        for (int k = kh*96; k < kh*96 + 96; ++k) {
            float dv = (k < 1024) ? h2b[k*32 + b] : cp[k - 1024];
            s = fmaf(dv, sw[k], s);
        }
        s_lds[tid] = s;   // tid = b*16 + kh
        __syncthreads();
        if (tid < 32) {
            float z = 0.f;
#pragma unroll
            for (int i = 0; i < 16; ++i) z += s_lds[tid*16 + i];
            out[OUT_GATE + tid*400 + t2] = sigf(z + sb[0]);
        }
    }
}

// ================================================================
// Phase kernel P2: blocks 0-31 lstm1-gates+attention+ctx(t)
//                  | 32-63 lstm2-gates(t-1)
// ================================================================
__global__ void __launch_bounds__(1024) kernel_P2(
    const float* __restrict__ mp, const float* __restrict__ l1b, const float* __restrict__ l2b,
    const float* __restrict__ wq, const float* __restrict__ vvec,
    const float* __restrict__ lconv, const float* __restrict__ ldense,
    float* __restrict__ ws, float* __restrict__ out, int t)
{
    __shared__ float s_attw[200], s_cum[200];
    __shared__ float s_hid[1024], s_q[128], s_ex[200], s_den[1];
    __shared__ float s_co[200*33];
    __shared__ float s_red[1024];
    const int tid = threadIdx.x, bid = blockIdx.x;
    float* in1m = ws + OFF_IN1T - 8192;
    float* in2T = ws + OFF_IN2T;
    float* zp1  = ws + OFF_ZP1;
    float* zp2  = ws + OFF_ZP2;
    float* ctxp = ws + OFF_CTXP;
    float* h2bb = ws + OFF_H2B;
    float* c1a  = ws + OFF_C1;
    float* c2a  = ws + OFF_C2;
    float* attw = ws + OFF_ATTW;
    float* cum  = ws + OFF_CUM;
    const float* pm = ws + OFF_PM;

    if (bid < 32) {
        if (t >= TSTEPS) return;
        const int b = bid;
        {   // LSTM1 gates
            int u = tid;
            float zi = l1b[u], zf = l1b[1024+u], zg = l1b[2048+u], zo = l1b[3072+u];
#pragma unroll
            for (int kc = 0; kc < KSP1; ++kc) {
                const float* zr = zp1 + (size_t)(kc*32 + b)*4096;
                zi += zr[u]; zf += zr[1024+u]; zg += zr[2048+u]; zo += zr[3072+u];
            }
            float c = sigf(zf)*c1a[b*1024+u] + sigf(zi)*tanhf_(zg);
            float h = sigf(zo)*tanhf_(c);
            c1a[b*1024+u] = c;
            s_hid[u] = h;
            in1m[(768+u)*32 + b] = h;       // for gemv1(t+1)
            in2T[u*32 + b] = h;             // for gemv2(t)
        }
        if (tid < 200) { s_attw[tid] = attw[b*200 + tid]; s_cum[tid] = cum[b*200 + tid]; }
        __syncthreads();
        {   // q partials: 8 k-strips x 128 a
            int a = tid & 127, kq = tid >> 7;
            float s = 0.f;
#pragma unroll 8
            for (int k = kq*128; k < kq*128 + 128; ++k)
                s = fmaf(s_hid[k], wq[k*128 + a], s);
            s_red[tid] = s;
        }
        __syncthreads();
        if (tid < 128) {
            float s = 0.f;
#pragma unroll
            for (int q = 0; q < 8; ++q) s += s_red[q*128 + tid];
            s_q[tid] = tanhf_(s);
        }
        // location conv (t-1 attw/cum from LDS)
        for (int idx = tid; idx < 6400; idx += 1024) {
            int tl = idx >> 5, f = idx & 31;
            float s = 0.f;
            for (int dw = 0; dw < 31; ++dw) {
                int tg = tl - 15 + dw;
                if (tg >= 0 && tg < 200) {
                    s = fmaf(s_attw[tg], lconv[(dw*2+0)*32 + f], s);
                    s = fmaf(s_cum[tg],  lconv[(dw*2+1)*32 + f], s);
                }
            }
            s_co[tl*33 + f] = s;
        }
        __syncthreads();
        // energies: 200 t x 4 lanes x 32 a
        if (tid < 800) {
            int tl = tid >> 2, aq = tid & 3;
            const float* pmrow = pm + (b*200 + tl)*128;
            float e = 0.f;
#pragma unroll 2
            for (int a = aq*32; a < aq*32 + 32; ++a) {
                float s = 0.f;
#pragma unroll
                for (int f = 0; f < 32; ++f) s = fmaf(s_co[tl*33 + f], ldense[f*128 + a], s);
                float en = tanhf_(s_q[a] + tanhf_(s) + pmrow[a]);
                e = fmaf(en, vvec[a], e);
            }
            e += __shfl_xor(e, 1, 4);
            e += __shfl_xor(e, 2, 4);
            if (aq == 0) s_ex[tl] = __expf(e);   // |e| <= ||v||_1 ~ 5: exp safe
        }
        __syncthreads();
        if (tid < 64) {
            float s = 0.f;
            for (int i = tid; i < 200; i += 64) s += s_ex[i];
            for (int off = 32; off; off >>= 1) s += __shfl_down(s, off, 64);
            if (tid == 0) s_den[0] = s;
        }
        __syncthreads();
        if (tid < 200) {
            float w = s_ex[tid] / s_den[0];
            s_attw[tid] = w;
            attw[b*200 + tid] = w;
            cum[b*200 + tid] = s_cum[tid] + w;
            out[OUT_ALIGN + (b*400 + t)*200 + tid] = w;
        }
        __syncthreads();
        {   // context = att_w @ memory
            int d = tid & 511, th = tid >> 9;
            float s = 0.f;
#pragma unroll 10
            for (int tt = th*100; tt < th*100 + 100; ++tt)
                s = fmaf(s_attw[tt], mp[(b*200 + tt)*512 + d], s);
            s_red[tid] = s;
        }
        __syncthreads();
        if (tid < 512) {
            float cv = s_red[tid] + s_red[512 + tid];
            ctxp[(size_t)(t & 3)*16384 + b*512 + tid] = cv;
            in1m[(256 + tid)*32 + b] = cv;     // for gemv1(t+1)
            in2T[(1024 + tid)*32 + b] = cv;    // for gemv2(t)
        }
    } else {
        if (t < 1 || t > TSTEPS) return;
        // LSTM2 gates, step t-1
        const int b = bid - 32, t1 = t - 1;
        float* h2b = h2bb + (size_t)(t1 & 1)*32768;
        int u = tid;
        float zi = l2b[u], zf = l2b[1024+u], zg = l2b[2048+u], zo = l2b[3072+u];
#pragma unroll
        for (int kc = 0; kc < KSP2; ++kc) {
            const float* zr = zp2 + (size_t)(kc*32 + b)*4096;
            zi += zr[u]; zf += zr[1024+u]; zg += zr[2048+u]; zo += zr[3072+u];
        }
        float c = sigf(zf)*c2a[b*1024+u] + sigf(zi)*tanhf_(zg);
        float h = sigf(zo)*tanhf_(c);
        c2a[b*1024+u] = c;
        in2T[(1536+u)*32 + b] = h;      // for gemv2(t)
        h2b[u*32 + b] = h;              // for mel/stop(t-1) later
    }
}

extern "C" void kernel_launch(void* const* d_in, const int* in_sizes, int n_in,
                              void* d_out, int out_size, void* d_ws, size_t ws_size,
                              hipStream_t stream) {
    (void)in_sizes; (void)n_in; (void)out_size;
    const float* mp    = (const float*)d_in[0];
    const float* dec   = (const float*)d_in[1];
    const float* pw0   = (const float*)d_in[2];
    const float* pb0   = (const float*)d_in[3];
    const float* pw1   = (const float*)d_in[4];
    const float* pb1   = (const float*)d_in[5];
    const float* l1k   = (const float*)d_in[6];
    const float* l1r   = (const float*)d_in[7];
    const float* l1b   = (const float*)d_in[8];
    const float* l2k   = (const float*)d_in[9];
    const float* l2r   = (const float*)d_in[10];
    const float* l2b   = (const float*)d_in[11];
    const float* wq    = (const float*)d_in[12];
    const float* wm    = (const float*)d_in[13];
    const float* vvec  = (const float*)d_in[14];
    const float* lconv = (const float*)d_in[15];
    const float* ldns  = (const float*)d_in[16];
    const float* fw    = (const float*)d_in[17];
    const float* fb    = (const float*)d_in[18];
    const float* sw    = (const float*)d_in[19];
    const float* sb    = (const float*)d_in[20];
    float* ws  = (float*)d_ws;
    float* out = (float*)d_out;

    if (ws_size < (size_t)WS_FLOATS * sizeof(float)) return;

    prenet_kernel<<<dim3(400, 32), 256, 0, stream>>>(dec, pw0, pb0, pw1, pb1, ws);
    pmem_kernel  <<<dim3(200, 32), 128, 0, stream>>>(mp, wm, ws);
    zero_kernel  <<<256, 256, 0, stream>>>(ws);

    // t=0..399: full steps; t=400: gemv2(399)+gates2(399)+mel/stop(398);
    // t=401 (P1 only): mel/stop(399).
    for (int t = 0; t <= TSTEPS; ++t) {
        kernel_P1<<<521, 512, 0, stream>>>(l1k, l1r, l2k, l2r, fw, fb, sw, sb, ws, out, t);
        kernel_P2<<<64, 1024, 0, stream>>>(mp, l1b, l2b, wq, vvec, lconv, ldns, ws, out, t);
    }
    kernel_P1<<<521, 512, 0, stream>>>(l1k, l1r, l2k, l2r, fw, fb, sw, sb, ws, out, TSTEPS + 1);
}

// Round 5
// 101371.393 us; speedup vs baseline: 1.0880x; 1.0880x over previous
//
#include <hip/hip_runtime.h>
#include <math.h>

// ---------------- problem constants ----------------
#define TSTEPS 400

// GEMV1: K1=1792 (x 0..255 bf16 | ctx 256..767 | h1 768..1791), W split at 768
//   224 blocks = 32 colgrp(128 cols) x 7 ksp(256 k = 8 chunks of 32)
// GEMV2: K2=2560 (h1 0..1023 | ctx 1024..1535 | h2 1536..2559), W split at 1536
//   256 blocks = 32 colgrp(128 cols) x 8 ksp(320 k = 10 chunks of 32)
// Weight stream: global_load_lds 16B, 16KB chunks, double-buffered.
#define KSP1 7
#define KSP2 8

// ---------------- workspace layout (float offsets) ----------------
#define OFF_XPRE  0u          // prenet out, BF16 [t][k][b]: 400*256*32 ushort = 1,638,400 float-slots
#define OFF_PM    1638400u    // tanh(memory@wm) fp32 [b][t][128]  (819,200)
#define OFF_IN1T  2457600u    // lstm1 input rows 256..1791, [(k-256)][b] (49,152)
#define OFF_IN2T  2506752u    // lstm2 input rows [k][b] (81,920)
#define OFF_ZP1   2588672u    // gemv1 partials [7][32][4096] (917,504)
#define OFF_ZP2   3506176u    // gemv2 partials [8][32][4096] (1,048,576)
#define OFF_CTXP  4554752u    // ctx 4-deep buffer [t&3][b][512] (65,536)
#define OFF_H2B   4620288u    // h2 2-deep buffer [parity][k][b] (65,536)
#define OFF_C1    4685824u    // c1 [b][1024] (32,768)
#define OFF_C2    4718592u    // c2 (32,768)
#define OFF_ATTW  4751360u    // att_w [b][200] (6,400)
#define OFF_CUM   4757760u    // att_w_cum (6,400)
#define WS_FLOATS 4764160u    // 19.06 MB (<= proven-available 24.9 MB)

// output layout (floats)
#define OUT_GATE  1024000   // 32*80*400
#define OUT_ALIGN 1036800   // + 32*400

__device__ __forceinline__ float sigf(float x)   { return 1.f / (1.f + __expf(-x)); }
__device__ __forceinline__ float tanhf_(float x) { return 1.f - 2.f / (__expf(2.f*x) + 1.f); }

// async global->LDS, 16B per lane. LDS dest = wave-uniform base + lane*16.
__device__ __forceinline__ void gload_lds16(const float* g, float* l) {
    __builtin_amdgcn_global_load_lds((const __attribute__((address_space(1))) void*)g,
                                     (__attribute__((address_space(3))) void*)l, 16, 0, 0);
}

// ---------------- P1: prenet for all 400 frames -> bf16 [t][k][b] ----------------
__global__ void __launch_bounds__(256) prenet_kernel(
    const float* __restrict__ dec, const float* __restrict__ w0, const float* __restrict__ b0,
    const float* __restrict__ w1, const float* __restrict__ b1, float* __restrict__ ws)
{
    __shared__ float s_in[80];
    __shared__ float s_h0[256];
    int t = blockIdx.x, b = blockIdx.y, tid = threadIdx.x;
    if (tid < 80) s_in[tid] = (t == 0) ? 0.f : dec[b*32000 + tid*400 + (t-1)];
    __syncthreads();
    float s = b0[tid];
    for (int m = 0; m < 80; ++m) s = fmaf(s_in[m], w0[m*256 + tid], s);
    s_h0[tid] = fmaxf(s, 0.f);
    __syncthreads();
    float s2 = b1[tid];
    for (int k = 0; k < 256; ++k) s2 = fmaf(s_h0[k], w1[k*256 + tid], s2);
    float v = fmaxf(s2, 0.f);
    unsigned u = __float_as_uint(v);
    u += 0x7fffu + ((u >> 16) & 1u);                     // RNE to bf16
    ((unsigned short*)(ws + OFF_XPRE))[(size_t)t*8192 + tid*32 + b] = (unsigned short)(u >> 16);
}

// ---------------- P2: processed_memory = tanh(memory @ wm), fp32 ----------------
__global__ void __launch_bounds__(128) pmem_kernel(
    const float* __restrict__ mp, const float* __restrict__ wm, float* __restrict__ ws)
{
    int t = blockIdx.x, b = blockIdx.y, a = threadIdx.x;
    const float* mrow = mp + (b*200 + t)*512;
    float s = 0.f;
    for (int d = 0; d < 512; ++d) s = fmaf(mrow[d], wm[d*128 + a], s);
    ws[OFF_PM + (b*200 + t)*128 + a] = tanhf_(s);
}

// ---------------- P3: zero recurrent state ----------------
__global__ void __launch_bounds__(256) zero_kernel(float* __restrict__ ws)
{
    int gid = blockIdx.x*256 + threadIdx.x, gsz = gridDim.x*256;
    for (int i = gid; i < 49152; i += gsz) ws[OFF_IN1T + i] = 0.f;
    for (int i = gid; i < 81920; i += gsz) ws[OFF_IN2T + i] = 0.f;
    for (int i = gid; i < 32768; i += gsz) { ws[OFF_C1 + i] = 0.f; ws[OFF_C2 + i] = 0.f; }
    for (int i = gid; i < 65536; i += gsz) { ws[OFF_CTXP + i] = 0.f; ws[OFF_H2B + i] = 0.f; }
    for (int i = gid; i < 6400;  i += gsz) { ws[OFF_ATTW + i] = 0.f; ws[OFF_CUM + i] = 0.f; }
}

// ================================================================
// Phase kernel P1: gemv1(t) [blocks 0..223] || gemv2(t-1) [blocks 224..479]
// 512 thr = 32 jq(4 cols) x 16 bq(2 batches); full-k per thread (no combine).
// Weight tile streamed via global_load_lds in 16KB chunks (32 k x 128 cols),
// double-buffered: in-flight bytes = 16KB/block, 32KB/CU.
// LDS: s_x (<=40KB) + s_w 32KB = 72KB -> 2 blocks/CU.
// ================================================================
__global__ void __launch_bounds__(512, 4) kernel_P1(
    const float* __restrict__ l1k, const float* __restrict__ l1r,
    const float* __restrict__ l2k, const float* __restrict__ l2r,
    float* __restrict__ ws, int t)
{
    __shared__ float s_x[10240];   // x slice [k][32 b]
    __shared__ float s_w[8192];    // 2 chunks x (32 k x 128 cols)
    const int tid = threadIdx.x, bid = blockIdx.x;
    const int jq = tid & 31, bq = tid >> 5;     // 32 jq x 16 bq
    const int lane = tid & 63, wid = tid >> 6;  // 8 waves; rows wid*4..wid*4+3 per chunk
    float4 a0 = make_float4(0.f,0.f,0.f,0.f), a1 = make_float4(0.f,0.f,0.f,0.f);

    if (bid < 224) {
        if (t >= TSTEPS) return;
        // -------- gemv1(t): 128 cols x 256 k, 8 chunks --------
        const int colgrp = bid & 31, ksp = bid >> 5;
        const int j = colgrp*128 + jq*4;
        // ksp 0..2 entirely in l1k (rows 0..767), ksp 3..6 in l1r
        const float* wbase = (ksp < 3) ? (l1k + (size_t)ksp*256*4096)
                                       : (l1r + (size_t)(ksp-3)*256*4096);
        // per-lane global src: row (lane>>5), col 16B strip (lane&31)
        const float* gsrc = wbase + colgrp*128 + (lane & 31)*4 + (size_t)(lane >> 5)*4096
                                  + (size_t)(wid*4)*4096;
        // wave-uniform LDS dst base (floats): rows wid*4.. of chunk buffer
        float* ldst = s_w + wid*4*128;

        // prologue: issue chunk 0, stage x, fence
        {
            const float* g = gsrc;                 // chunk 0 rows
            gload_lds16(g,            ldst);
            gload_lds16(g + 2*4096,   ldst + 2*128);
        }
        if (ksp == 0) {
            const uint4* src = (const uint4*)((const unsigned short*)(ws + OFF_XPRE) + (size_t)t*8192);
            for (int i = tid; i < 1024; i += 512) {
                uint4 p = src[i];
                float* d = s_x + i*8;
                d[0] = __uint_as_float(p.x << 16); d[1] = __uint_as_float(p.x & 0xffff0000u);
                d[2] = __uint_as_float(p.y << 16); d[3] = __uint_as_float(p.y & 0xffff0000u);
                d[4] = __uint_as_float(p.z << 16); d[5] = __uint_as_float(p.z & 0xffff0000u);
                d[6] = __uint_as_float(p.w << 16); d[7] = __uint_as_float(p.w & 0xffff0000u);
            }
        } else {
            const float4* src = (const float4*)(ws + OFF_IN1T - 8192 + (size_t)ksp*256*32);
            float4* dst = (float4*)s_x;
            for (int i = tid; i < 2048; i += 512) dst[i] = src[i];
        }
        asm volatile("s_waitcnt vmcnt(0)" ::: "memory");
        __syncthreads();

        const float* xb = s_x + bq*2;
        const float* wjb = s_w + jq*4;
        for (int c = 0; c < 8; ++c) {
            if (c + 1 < 8) {   // prefetch chunk c+1 into buffer (c+1)&1
                const float* g = gsrc + (size_t)(c + 1)*32*4096;
                float* lp = ldst + ((c + 1) & 1)*4096;
                gload_lds16(g,          lp);
                gload_lds16(g + 2*4096, lp + 2*128);
            }
            const float* wch = wjb + (c & 1)*4096;
            const float* xch = xb + c*32*32;
#pragma unroll 8
            for (int kk = 0; kk < 32; ++kk) {
                float4 w = *(const float4*)(wch + kk*128);
                float2 x = *(const float2*)(xch + kk*32);
                a0.x = fmaf(x.x, w.x, a0.x); a0.y = fmaf(x.x, w.y, a0.y);
                a0.z = fmaf(x.x, w.z, a0.z); a0.w = fmaf(x.x, w.w, a0.w);
                a1.x = fmaf(x.y, w.x, a1.x); a1.y = fmaf(x.y, w.y, a1.y);
                a1.z = fmaf(x.y, w.z, a1.z); a1.w = fmaf(x.y, w.w, a1.w);
            }
            asm volatile("s_waitcnt vmcnt(0)" ::: "memory");
            __syncthreads();
        }
        float* zp1 = ws + OFF_ZP1;
        *(float4*)(zp1 + (size_t)(ksp*32 + bq*2 + 0)*4096 + j) = a0;
        *(float4*)(zp1 + (size_t)(ksp*32 + bq*2 + 1)*4096 + j) = a1;
    } else {
        if (t < 1 || t > TSTEPS) return;
        // -------- gemv2(t-1): 128 cols x 320 k, 10 chunks --------
        const int g2 = bid - 224;
        const int colgrp = g2 & 31, ksp = g2 >> 5;
        const int j = colgrp*128 + jq*4;
        const int kbase = ksp*320;
        float* ldst = s_w + wid*4*128;

        // chunk base-ptr select (1536 split is 32-aligned -> uniform per chunk)
        // prologue: issue chunk 0, stage x, fence
        {
            int kg = kbase;
            const float* wb2 = (kg < 1536) ? (l2k + (size_t)kg*4096)
                                           : (l2r + (size_t)(kg - 1536)*4096);
            const float* g = wb2 + colgrp*128 + (lane & 31)*4 + (size_t)(lane >> 5)*4096
                                 + (size_t)(wid*4)*4096;
            gload_lds16(g,          ldst);
            gload_lds16(g + 2*4096, ldst + 2*128);
        }
        {
            const float4* src = (const float4*)(ws + OFF_IN2T + (size_t)kbase*32);
            float4* dst = (float4*)s_x;
            for (int i = tid; i < 2560; i += 512) dst[i] = src[i];
        }
        asm volatile("s_waitcnt vmcnt(0)" ::: "memory");
        __syncthreads();

        const float* xb = s_x + bq*2;
        const float* wjb = s_w + jq*4;
        for (int c = 0; c < 10; ++c) {
            if (c + 1 < 10) {
                int kg = kbase + (c + 1)*32;
                const float* wb2 = (kg < 1536) ? (l2k + (size_t)kg*4096)
                                               : (l2r + (size_t)(kg - 1536)*4096);
                const float* g = wb2 + colgrp*128 + (lane & 31)*4 + (size_t)(lane >> 5)*4096
                                     + (size_t)(wid*4)*4096;
                float* lp = ldst + ((c + 1) & 1)*4096;
                gload_lds16(g,          lp);
                gload_lds16(g + 2*4096, lp + 2*128);
            }
            const float* wch = wjb + (c & 1)*4096;
            const float* xch = xb + c*32*32;
#pragma unroll 8
            for (int kk = 0; kk < 32; ++kk) {
                float4 w = *(const float4*)(wch + kk*128);
                float2 x = *(const float2*)(xch + kk*32);
                a0.x = fmaf(x.x, w.x, a0.x); a0.y = fmaf(x.x, w.y, a0.y);
                a0.z = fmaf(x.x, w.z, a0.z); a0.w = fmaf(x.x, w.w, a0.w);
                a1.x = fmaf(x.y, w.x, a1.x); a1.y = fmaf(x.y, w.y, a1.y);
                a1.z = fmaf(x.y, w.z, a1.z); a1.w = fmaf(x.y, w.w, a1.w);
            }
            asm volatile("s_waitcnt vmcnt(0)" ::: "memory");
            __syncthreads();
        }
        float* zp2 = ws + OFF_ZP2;
        *(float4*)(zp2 + (size_t)(ksp*32 + bq*2 + 0)*4096 + j) = a0;
        *(float4*)(zp2 + (size_t)(ksp*32 + bq*2 + 1)*4096 + j) = a1;
    }
}

// ================================================================
// Phase kernel P2: blocks 0-31 lstm1-gates+attention+ctx(t)
//                  | 32-63 lstm2-gates(t-1) | 64-73 mel(t-2) | 74 stop(t-2)
// ================================================================
__global__ void __launch_bounds__(1024) kernel_P2(
    const float* __restrict__ mp, const float* __restrict__ l1b, const float* __restrict__ l2b,
    const float* __restrict__ wq, const float* __restrict__ vvec,
    const float* __restrict__ lconv, const float* __restrict__ ldense,
    const float* __restrict__ fw, const float* __restrict__ fb,
    const float* __restrict__ sw, const float* __restrict__ sb,
    float* __restrict__ ws, float* __restrict__ out, int t)
{
    __shared__ float s_attw[200], s_cum[200];
    __shared__ float s_hid[1024], s_q[128], s_ex[200], s_den[1];
    __shared__ float s_co[200*33];
    __shared__ float s_red[1024];
    const int tid = threadIdx.x, bid = blockIdx.x;
    float* in1m = ws + OFF_IN1T - 8192;
    float* in2T = ws + OFF_IN2T;
    float* zp1  = ws + OFF_ZP1;
    float* zp2  = ws + OFF_ZP2;
    float* ctxp = ws + OFF_CTXP;
    float* h2bb = ws + OFF_H2B;
    float* c1a  = ws + OFF_C1;
    float* c2a  = ws + OFF_C2;
    float* attw = ws + OFF_ATTW;
    float* cum  = ws + OFF_CUM;
    const float* pm = ws + OFF_PM;

    if (bid < 32) {
        if (t >= TSTEPS) return;
        const int b = bid;
        {   // LSTM1 gates
            int u = tid;
            float zi = l1b[u], zf = l1b[1024+u], zg = l1b[2048+u], zo = l1b[3072+u];
#pragma unroll
            for (int kc = 0; kc < KSP1; ++kc) {
                const float* zr = zp1 + (size_t)(kc*32 + b)*4096;
                zi += zr[u]; zf += zr[1024+u]; zg += zr[2048+u]; zo += zr[3072+u];
            }
            float c = sigf(zf)*c1a[b*1024+u] + sigf(zi)*tanhf_(zg);
            float h = sigf(zo)*tanhf_(c);
            c1a[b*1024+u] = c;
            s_hid[u] = h;
            in1m[(768+u)*32 + b] = h;       // for gemv1(t+1)
            in2T[u*32 + b] = h;             // for gemv2(t)
        }
        if (tid < 200) { s_attw[tid] = attw[b*200 + tid]; s_cum[tid] = cum[b*200 + tid]; }
        __syncthreads();
        {   // q partials: 8 k-strips x 128 a
            int a = tid & 127, kq = tid >> 7;
            float s = 0.f;
#pragma unroll 8
            for (int k = kq*128; k < kq*128 + 128; ++k)
                s = fmaf(s_hid[k], wq[k*128 + a], s);
            s_red[tid] = s;
        }
        __syncthreads();
        if (tid < 128) {
            float s = 0.f;
#pragma unroll
            for (int q = 0; q < 8; ++q) s += s_red[q*128 + tid];
            s_q[tid] = tanhf_(s);
        }
        // location conv (t-1 attw/cum from LDS)
        for (int idx = tid; idx < 6400; idx += 1024) {
            int tl = idx >> 5, f = idx & 31;
            float s = 0.f;
            for (int dw = 0; dw < 31; ++dw) {
                int tg = tl - 15 + dw;
                if (tg >= 0 && tg < 200) {
                    s = fmaf(s_attw[tg], lconv[(dw*2+0)*32 + f], s);
                    s = fmaf(s_cum[tg],  lconv[(dw*2+1)*32 + f], s);
                }
            }
            s_co[tl*33 + f] = s;
        }
        __syncthreads();
        // energies: 200 t x 4 lanes x 32 a
        if (tid < 800) {
            int tl = tid >> 2, aq = tid & 3;
            const float* pmrow = pm + (b*200 + tl)*128;
            float e = 0.f;
#pragma unroll 2
            for (int a = aq*32; a < aq*32 + 32; ++a) {
                float s = 0.f;
#pragma unroll
                for (int f = 0; f < 32; ++f) s = fmaf(s_co[tl*33 + f], ldense[f*128 + a], s);
                float en = tanhf_(s_q[a] + tanhf_(s) + pmrow[a]);
                e = fmaf(en, vvec[a], e);
            }
            e += __shfl_xor(e, 1, 4);
            e += __shfl_xor(e, 2, 4);
            if (aq == 0) s_ex[tl] = __expf(e);   // |e| <= ||v||_1 ~ 5: exp safe
        }
        __syncthreads();
        if (tid < 64) {
            float s = 0.f;
            for (int i = tid; i < 200; i += 64) s += s_ex[i];
            for (int off = 32; off; off >>= 1) s += __shfl_down(s, off, 64);
            if (tid == 0) s_den[0] = s;
        }
        __syncthreads();
        if (tid < 200) {
            float w = s_ex[tid] / s_den[0];
            s_attw[tid] = w;
            attw[b*200 + tid] = w;
            cum[b*200 + tid] = s_cum[tid] + w;
            out[OUT_ALIGN + (b*400 + t)*200 + tid] = w;
        }
        __syncthreads();
        {   // context = att_w @ memory
            int d = tid & 511, th = tid >> 9;
            float s = 0.f;
#pragma unroll 10
            for (int tt = th*100; tt < th*100 + 100; ++tt)
                s = fmaf(s_attw[tt], mp[(b*200 + tt)*512 + d], s);
            s_red[tid] = s;
        }
        __syncthreads();
        if (tid < 512) {
            float cv = s_red[tid] + s_red[512 + tid];
            ctxp[(size_t)(t & 3)*16384 + b*512 + tid] = cv;
            in1m[(256 + tid)*32 + b] = cv;     // for gemv1(t+1)
            in2T[(1024 + tid)*32 + b] = cv;    // for gemv2(t)
        }
    } else if (bid < 64) {
        if (t < 1 || t > TSTEPS) return;
        // LSTM2 gates, step t-1
        const int b = bid - 32, t1 = t - 1;
        float* h2b = h2bb + (size_t)(t1 & 1)*32768;
        int u = tid;
        float zi = l2b[u], zf = l2b[1024+u], zg = l2b[2048+u], zo = l2b[3072+u];
#pragma unroll
        for (int kc = 0; kc < KSP2; ++kc) {
            const float* zr = zp2 + (size_t)(kc*32 + b)*4096;
            zi += zr[u]; zf += zr[1024+u]; zg += zr[2048+u]; zo += zr[3072+u];
        }
        float c = sigf(zf)*c2a[b*1024+u] + sigf(zi)*tanhf_(zg);
        float h = sigf(zo)*tanhf_(c);
        c2a[b*1024+u] = c;
        in2T[(1536+u)*32 + b] = h;      // for gemv2(t)
        h2b[u*32 + b] = h;              // for mel/stop(t-1) later
    } else if (bid < 74) {
        if (t < 2) return;
        // mel, step t-2 : 10 blocks x 8 mel-cols, 4 kh x 384 k
        const int t2 = t - 2;
        const int mc = bid - 64;
        const int m_l = tid & 7, b = (tid >> 3) & 31, kh = tid >> 8;
        const int m = mc*8 + m_l;
        const float* cp = ctxp + (size_t)((t2 & 3)*32 + b)*512;
        const float* h2b = h2bb + (size_t)(t2 & 1)*32768;
        float s = 0.f;
#pragma unroll 8
        for (int k = kh*384; k < kh*384 + 384; ++k) {
            float dv = (k < 1024) ? h2b[k*32 + b] : cp[k - 1024];
            s = fmaf(dv, fw[k*80 + m], s);
        }
        s_red[tid] = s;
        __syncthreads();
        if (tid < 256) {
            float v4 = s_red[tid] + s_red[256+tid] + s_red[512+tid] + s_red[768+tid];
            int b2 = tid >> 3, m2 = mc*8 + (tid & 7);
            out[(b2*80 + m2)*400 + t2] = v4 + fb[m2];
        }
    } else {
        if (t < 2) return;
        // stop gate, step t-2
        const int t2 = t - 2;
        const int b = tid >> 5, kh = tid & 31;
        const float* cp = ctxp + (size_t)((t2 & 3)*32 + b)*512;
        const float* h2b = h2bb + (size_t)(t2 & 1)*32768;
        float s = 0.f;
#pragma unroll 8
        for (int k = kh*48; k < kh*48 + 48; ++k) {
            float dv = (k < 1024) ? h2b[k*32 + b] : cp[k - 1024];
            s = fmaf(dv, sw[k], s);
        }
        s_red[b*32 + kh] = s;
        __syncthreads();
        if (tid < 32) {
            float z = 0.f;
#pragma unroll
            for (int i = 0; i < 32; ++i) z += s_red[tid*32 + i];
            out[OUT_GATE + tid*400 + t2] = sigf(z + sb[0]);
        }
    }
}

extern "C" void kernel_launch(void* const* d_in, const int* in_sizes, int n_in,
                              void* d_out, int out_size, void* d_ws, size_t ws_size,
                              hipStream_t stream) {
    (void)in_sizes; (void)n_in; (void)out_size;
    const float* mp    = (const float*)d_in[0];
    const float* dec   = (const float*)d_in[1];
    const float* pw0   = (const float*)d_in[2];
    const float* pb0   = (const float*)d_in[3];
    const float* pw1   = (const float*)d_in[4];
    const float* pb1   = (const float*)d_in[5];
    const float* l1k   = (const float*)d_in[6];
    const float* l1r   = (const float*)d_in[7];
    const float* l1b   = (const float*)d_in[8];
    const float* l2k   = (const float*)d_in[9];
    const float* l2r   = (const float*)d_in[10];
    const float* l2b   = (const float*)d_in[11];
    const float* wq    = (const float*)d_in[12];
    const float* wm    = (const float*)d_in[13];
    const float* vvec  = (const float*)d_in[14];
    const float* lconv = (const float*)d_in[15];
    const float* ldns  = (const float*)d_in[16];
    const float* fw    = (const float*)d_in[17];
    const float* fb    = (const float*)d_in[18];
    const float* sw    = (const float*)d_in[19];
    const float* sb    = (const float*)d_in[20];
    float* ws  = (float*)d_ws;
    float* out = (float*)d_out;

    if (ws_size < (size_t)WS_FLOATS * sizeof(float)) return;

    prenet_kernel<<<dim3(400, 32), 256, 0, stream>>>(dec, pw0, pb0, pw1, pb1, ws);
    pmem_kernel  <<<dim3(200, 32), 128, 0, stream>>>(mp, wm, ws);
    zero_kernel  <<<256, 256, 0, stream>>>(ws);

    // t=0..399: full steps; t=400: gemv2(399)+gates2(399)+mel/stop(398);
    // t=401 (P2 only): mel/stop(399).
    for (int t = 0; t <= TSTEPS; ++t) {
        kernel_P1<<<480, 512, 0, stream>>>(l1k, l1r, l2k, l2r, ws, t);
        kernel_P2<<<75, 1024, 0, stream>>>(mp, l1b, l2b, wq, vvec, lconv, ldns,
                                           fw, fb, sw, sb, ws, out, t);
    }
    kernel_P2<<<75, 1024, 0, stream>>>(mp, l1b, l2b, wq, vvec, lconv, ldns,
                                       fw, fb, sw, sb, ws, out, TSTEPS + 1);
}